// Round 1
// baseline (149.676 us; speedup 1.0000x reference)
//
#include <hip/hip_runtime.h>
#include <hip/hip_bf16.h>

typedef unsigned short ushort_t;
typedef __attribute__((ext_vector_type(8))) short bf16x8;
typedef __attribute__((ext_vector_type(4))) float f32x4;

typedef const __attribute__((address_space(1))) void gvoid_t;
typedef __attribute__((address_space(3))) void lvoid_t;

__device__ __forceinline__ void gload_lds16(const void* g, void* l) {
  __builtin_amdgcn_global_load_lds((gvoid_t*)g, (lvoid_t*)l, 16, 0, 0);
}

__device__ __forceinline__ ushort_t f2bf(float f) {
  union { float f; unsigned u; } a;
  a.f = f;
  unsigned r = (a.u + 0x7FFFu + ((a.u >> 16) & 1u)) >> 16;  // RN-even
  return (ushort_t)r;
}

// ---------------------------------------------------------------------------
// Prep: fp32 -> bf16 copies of x and y, plus per-row sum of squares.
// One block per row (512 floats), 128 threads x float4.
// ---------------------------------------------------------------------------
__global__ __launch_bounds__(128) void rbf_prep(
    const float* __restrict__ x, const float* __restrict__ y,
    ushort_t* __restrict__ xb, ushort_t* __restrict__ yb,
    float* __restrict__ xsq, float* __restrict__ ysq,
    int N, int M, int D) {
  int row = blockIdx.x;
  const float* src;
  ushort_t* dst;
  float* sq;
  if (row < N) {
    src = x + (size_t)row * D;
    dst = xb + (size_t)row * D;
    sq = xsq + row;
  } else {
    int r = row - N;
    src = y + (size_t)r * D;
    dst = yb + (size_t)r * D;
    sq = ysq + r;
  }
  int t = threadIdx.x;
  float4 v = reinterpret_cast<const float4*>(src)[t];
  float s = v.x * v.x + v.y * v.y + v.z * v.z + v.w * v.w;
  ushort4 o;
  o.x = f2bf(v.x);
  o.y = f2bf(v.y);
  o.z = f2bf(v.z);
  o.w = f2bf(v.w);
  reinterpret_cast<ushort4*>(dst)[t] = o;

  // reduce 128 threads (2 waves)
  #pragma unroll
  for (int off = 32; off > 0; off >>= 1) s += __shfl_down(s, off, 64);
  __shared__ float red[2];
  if ((t & 63) == 0) red[t >> 6] = s;
  __syncthreads();
  if (t == 0) sq[0] = red[0] + red[1];
}

// ---------------------------------------------------------------------------
// Main GEMM + RBF epilogue. m97-structure: 128x128 tile, BK=32, 4 waves,
// mfma_f32_16x16x32_bf16 4x4 repeat, global_load_lds width=16 staging.
// Both operands K-contiguous (x[i][k], y[j][k]) -> all frags are ds_read_b128.
// ---------------------------------------------------------------------------
#define BM 128
#define BN 128
#define BK 32

__global__ __launch_bounds__(256) void rbf_gemm(
    const ushort_t* __restrict__ xb, const ushort_t* __restrict__ yb,
    const float* __restrict__ xsq, const float* __restrict__ ysq,
    const float* __restrict__ gptr, float* __restrict__ out,
    int N, int M, int D) {
  __shared__ ushort_t As[BM * BK];  // 8 KB
  __shared__ ushort_t Bs[BN * BK];  // 8 KB

  // XCD-aware bijective swizzle (nwg divisible by 8 here: 4096)
  int nwg = gridDim.x;
  int bid = blockIdx.x;
  int cpx = nwg >> 3;
  int swz = (bid & 7) * cpx + (bid >> 3);
  int nbn = M / BN;
  int brow = (swz / nbn) * BM;
  int bcol = (swz % nbn) * BN;

  int tid = threadIdx.x;
  int wv = tid >> 6;           // wave 0..3
  int lane = tid & 63;
  int wr = wv >> 1, wc = wv & 1;  // 2x2 wave quadrants of 64x64
  int fr = lane & 15;          // fragment row/col within 16
  int fq = lane >> 4;          // 0..3: k-group for A/B, row-group for C
  int lrow = tid >> 2;         // staging: row within 64-row chunk
  int kof = (tid & 3) << 3;    // staging: k offset (8 bf16 = 16 B)

  f32x4 acc[4][4];
  #pragma unroll
  for (int m = 0; m < 4; ++m)
    #pragma unroll
    for (int n = 0; n < 4; ++n)
      acc[m][n] = (f32x4){0.f, 0.f, 0.f, 0.f};

  const size_t Dz = (size_t)D;
  for (int k0 = 0; k0 < D; k0 += BK) {
    // Stage A tile (128x32 bf16 = 8KB, 2 issues) + B tile (same).
    // LDS dest is linear: wave-uniform base + lane*16.
    #pragma unroll
    for (int i = 0; i < 2; ++i) {
      gload_lds16(xb + (size_t)(brow + i * 64 + lrow) * Dz + k0 + kof,
                  (void*)(As + (i * 64 + wv * 16) * BK));
      gload_lds16(yb + (size_t)(bcol + i * 64 + lrow) * Dz + k0 + kof,
                  (void*)(Bs + (i * 64 + wv * 16) * BK));
    }
    __syncthreads();  // compiler emits vmcnt(0) drain before barrier

    bf16x8 af[4], bf[4];
    #pragma unroll
    for (int m = 0; m < 4; ++m)
      af[m] = *reinterpret_cast<const bf16x8*>(
          &As[(wr * 64 + m * 16 + fr) * BK + fq * 8]);
    #pragma unroll
    for (int n = 0; n < 4; ++n)
      bf[n] = *reinterpret_cast<const bf16x8*>(
          &Bs[(wc * 64 + n * 16 + fr) * BK + fq * 8]);

    #pragma unroll
    for (int m = 0; m < 4; ++m)
      #pragma unroll
      for (int n = 0; n < 4; ++n)
        acc[m][n] = __builtin_amdgcn_mfma_f32_16x16x32_bf16(
            af[m], bf[n], acc[m][n], 0, 0, 0);
    __syncthreads();
  }

  // Epilogue: d2 = |x|^2 + |y|^2 - 2 x.y ; out = exp(-gamma*d2)
  // C/D layout (verified m89/m91): row = fq*4 + reg, col = fr.
  float gamma = gptr[0];
  #pragma unroll
  for (int m = 0; m < 4; ++m) {
    #pragma unroll
    for (int r = 0; r < 4; ++r) {
      int i = brow + wr * 64 + m * 16 + fq * 4 + r;
      float xs = xsq[i];
      size_t rowoff = (size_t)i * M;
      #pragma unroll
      for (int n = 0; n < 4; ++n) {
        int j = bcol + wc * 64 + n * 16 + fr;
        float d2 = xs + ysq[j] - 2.0f * acc[m][n][r];
        d2 = fmaxf(d2, 0.0f);
        out[rowoff + j] = __expf(-gamma * d2);
      }
    }
  }
}

// ---------------------------------------------------------------------------
// Fallback (only if workspace is too small): fp32 LDS-tiled, slow but correct.
// ---------------------------------------------------------------------------
__global__ __launch_bounds__(256) void rbf_naive(
    const float* __restrict__ x, const float* __restrict__ y,
    const float* __restrict__ gptr, float* __restrict__ out,
    int N, int M, int D) {
  __shared__ float xs[16][17];
  __shared__ float ys[16][17];
  int nbn = M / 16;
  int brow = (blockIdx.x / nbn) * 16;
  int bcol = (blockIdx.x % nbn) * 16;
  int ti = threadIdx.x >> 4, tj = threadIdx.x & 15;
  float dacc = 0.f, xacc = 0.f, yacc = 0.f;
  for (int k0 = 0; k0 < D; k0 += 16) {
    xs[ti][tj] = x[(size_t)(brow + ti) * D + k0 + tj];
    ys[ti][tj] = y[(size_t)(bcol + ti) * D + k0 + tj];
    __syncthreads();
    #pragma unroll
    for (int kk = 0; kk < 16; ++kk) {
      float xv = xs[ti][kk], yv = ys[tj][kk];
      dacc += xv * yv;
      xacc += xv * xv;
      yacc += yv * yv;
    }
    __syncthreads();
  }
  float gamma = gptr[0];
  float d2 = fmaxf(xacc + yacc - 2.f * dacc, 0.f);
  out[(size_t)(brow + ti) * M + (bcol + tj)] = __expf(-gamma * d2);
}

// ---------------------------------------------------------------------------
extern "C" void kernel_launch(void* const* d_in, const int* in_sizes, int n_in,
                              void* d_out, int out_size, void* d_ws,
                              size_t ws_size, hipStream_t stream) {
  const float* x = (const float*)d_in[0];
  const float* y = (const float*)d_in[1];
  const float* g = (const float*)d_in[2];
  float* out = (float*)d_out;

  const int D = 512;
  const int N = in_sizes[0] / D;
  const int M = in_sizes[1] / D;

  // ws layout: xb[N*D] bf16 | yb[M*D] bf16 | xsq[N] f32 | ysq[M] f32
  size_t need = (size_t)(N + M) * D * sizeof(ushort_t) +
                (size_t)(N + M) * sizeof(float);

  bool shapes_ok = (N % BM == 0) && (M % BN == 0) && (D % BK == 0);

  if (ws_size >= need && shapes_ok) {
    ushort_t* xb = (ushort_t*)d_ws;
    ushort_t* yb = xb + (size_t)N * D;
    float* xsq = (float*)(yb + (size_t)M * D);
    float* ysq = xsq + N;

    rbf_prep<<<N + M, 128, 0, stream>>>(x, y, xb, yb, xsq, ysq, N, M, D);
    int nwg = (N / BM) * (M / BN);
    rbf_gemm<<<nwg, 256, 0, stream>>>(xb, yb, xsq, ysq, g, out, N, M, D);
  } else {
    rbf_naive<<<(N / 16) * (M / 16), 256, 0, stream>>>(x, y, g, out, N, M, D);
  }
}

// Round 2
// 124.525 us; speedup vs baseline: 1.2020x; 1.2020x over previous
//
#include <hip/hip_runtime.h>
#include <hip/hip_bf16.h>

typedef unsigned short u16;
typedef __attribute__((ext_vector_type(8))) short bf16x8;
typedef __attribute__((ext_vector_type(4))) float f32x4;

typedef const __attribute__((address_space(1))) void gvoid_t;
typedef __attribute__((address_space(3))) void lvoid_t;

__device__ __forceinline__ void gload_lds16(const void* g, void* l) {
  __builtin_amdgcn_global_load_lds((gvoid_t*)g, (lvoid_t*)l, 16, 0, 0);
}

__device__ __forceinline__ u16 f2bf(float f) {
  union { float f; unsigned u; } a;
  a.f = f;
  unsigned r = (a.u + 0x7FFFu + ((a.u >> 16) & 1u)) >> 16;  // RN-even
  return (u16)r;
}

// ---------------------------------------------------------------------------
// Prep: fp32 -> bf16 copies of x and y, plus per-row sum of squares.
// ---------------------------------------------------------------------------
__global__ __launch_bounds__(128) void rbf_prep(
    const float* __restrict__ x, const float* __restrict__ y,
    u16* __restrict__ xb, u16* __restrict__ yb,
    float* __restrict__ xsq, float* __restrict__ ysq,
    int N, int M, int D) {
  int row = blockIdx.x;
  const float* src;
  u16* dst;
  float* sq;
  if (row < N) {
    src = x + (size_t)row * D;
    dst = xb + (size_t)row * D;
    sq = xsq + row;
  } else {
    int r = row - N;
    src = y + (size_t)r * D;
    dst = yb + (size_t)r * D;
    sq = ysq + r;
  }
  int t = threadIdx.x;
  float4 v = reinterpret_cast<const float4*>(src)[t];
  float s = v.x * v.x + v.y * v.y + v.z * v.z + v.w * v.w;
  ushort4 o;
  o.x = f2bf(v.x);
  o.y = f2bf(v.y);
  o.z = f2bf(v.z);
  o.w = f2bf(v.w);
  reinterpret_cast<ushort4*>(dst)[t] = o;
  #pragma unroll
  for (int off = 32; off > 0; off >>= 1) s += __shfl_down(s, off, 64);
  __shared__ float red[2];
  if ((t & 63) == 0) red[t >> 6] = s;
  __syncthreads();
  if (t == 0) sq[0] = red[0] + red[1];
}

// ---------------------------------------------------------------------------
// 256x256 deep-pipelined GEMM + RBF epilogue.
//   8 waves (2Mx4N), BK=64, LDS [2 buf][A,B][256x64] bf16 = 128 KiB.
//   Per K-tile: 4 phases {ds_read quadrant; setprio(1); 16 MFMA; setprio(0); bar}.
//   kt+2 staged (8 global_load_lds/wave) AFTER end-of-iter lgkmcnt(0)+barrier
//   (buffer tenant fully read); top-of-iter counted vmcnt(8) keeps kt+2's loads
//   in flight across the whole iteration (T3+T4). st_16x32 XOR swizzle (T2):
//   inverse-swizzled global source + swizzled ds_read, linear gload_lds dest.
// ---------------------------------------------------------------------------
#define BM 256
#define BN 256
#define BK 64

__global__ __launch_bounds__(512, 2) void rbf_gemm(
    const u16* __restrict__ xb, const u16* __restrict__ yb,
    const float* __restrict__ xsq, const float* __restrict__ ysq,
    const float* __restrict__ gptr, float* __restrict__ out,
    int N, int M, int D) {
  __shared__ u16 lds[2][2][BM * BK];  // 128 KiB

  // XCD-aware swizzle (nwg = 1024, divisible by 8 -> bijective)
  int nwg = gridDim.x;
  int bid = blockIdx.x;
  int cpx = nwg >> 3;
  int swz = (bid & 7) * cpx + (bid >> 3);
  int nbn = M / BN;
  int brow = (swz / nbn) * BM;
  int bcol = (swz % nbn) * BN;

  int tid = threadIdx.x;
  int w = tid >> 6;    // wave 0..7
  int lane = tid & 63;
  int wm = w >> 2;     // 0..1 : row half (128 rows)
  int wn = w & 3;      // 0..3 : col quarter (64 cols)
  int fr = lane & 15;
  int fq = lane >> 4;

  // --- staging addresses (wave w stages rows w*32..w*32+31 of each tile) ---
  // physical LDS byte (linear, lane*16) -> logical byte ^= ((phys>>9)&1)<<5
  int srow = lane >> 3;                                 // 0..7
  int scol = ((lane & 7) * 8) ^ ((lane >= 32) ? 16 : 0);  // inverse-swizzled src col
  const u16* xsrc = xb + (size_t)(brow + w * 32 + srow) * D + scol;
  const u16* ysrc = yb + (size_t)(bcol + w * 32 + srow) * D + scol;
  int sdst = w * 4 * 512;  // LDS elem offset of this wave's first 1KB subtile

  // --- fragment read offsets (swizzled read: col ^= (row&4)?16:0) ---
  int cswz = (fr & 4) ? 16 : 0;
  int colx0 = (fq * 8) ^ cswz;         // kk = 0
  int colx1 = (32 + fq * 8) ^ cswz;    // kk = 1
  int aoff0 = (wm * 128 + fr) * 64 + colx0;
  int aoff1 = (wm * 128 + fr) * 64 + colx1;
  int boff0 = (wn * 64 + fr) * 64 + colx0;
  int boff1 = (wn * 64 + fr) * 64 + colx1;

  f32x4 acc[8][4];
  #pragma unroll
  for (int m = 0; m < 8; ++m)
    #pragma unroll
    for (int n = 0; n < 4; ++n)
      acc[m][n] = (f32x4){0.f, 0.f, 0.f, 0.f};

  auto stage = [&](int kt, int b) {
    const u16* xs = xsrc + kt * 64;
    const u16* ys = ysrc + kt * 64;
    u16* la = &lds[b][0][sdst];
    u16* lb = &lds[b][1][sdst];
    #pragma unroll
    for (int i = 0; i < 4; ++i)
      gload_lds16(xs + (size_t)i * 8 * D, la + i * 512);
    #pragma unroll
    for (int i = 0; i < 4; ++i)
      gload_lds16(ys + (size_t)i * 8 * D, lb + i * 512);
  };

#define PHASE(MH, NH, RA, RB)                                                  \
  {                                                                            \
    if (RA) {                                                                  \
      _Pragma("unroll") for (int mi = 0; mi < 4; ++mi) {                       \
        af[mi][0] = *(const bf16x8*)&A[aoff0 + (MH * 4 + mi) * 1024];          \
        af[mi][1] = *(const bf16x8*)&A[aoff1 + (MH * 4 + mi) * 1024];          \
      }                                                                        \
    }                                                                          \
    if (RB) {                                                                  \
      _Pragma("unroll") for (int ni = 0; ni < 2; ++ni) {                       \
        bf[ni][0] = *(const bf16x8*)&B[boff0 + (NH * 2 + ni) * 1024];          \
        bf[ni][1] = *(const bf16x8*)&B[boff1 + (NH * 2 + ni) * 1024];          \
      }                                                                        \
    }                                                                          \
    __builtin_amdgcn_s_setprio(1);                                             \
    _Pragma("unroll") for (int mi = 0; mi < 4; ++mi)                           \
      _Pragma("unroll") for (int ni = 0; ni < 2; ++ni) {                       \
        acc[MH * 4 + mi][NH * 2 + ni] =                                        \
            __builtin_amdgcn_mfma_f32_16x16x32_bf16(                           \
                af[mi][0], bf[ni][0], acc[MH * 4 + mi][NH * 2 + ni], 0, 0, 0); \
        acc[MH * 4 + mi][NH * 2 + ni] =                                        \
            __builtin_amdgcn_mfma_f32_16x16x32_bf16(                           \
                af[mi][1], bf[ni][1], acc[MH * 4 + mi][NH * 2 + ni], 0, 0, 0); \
      }                                                                        \
    __builtin_amdgcn_s_setprio(0);                                             \
  }

  int nkt = D >> 6;  // 8
  stage(0, 0);
  stage(1, 1);
  for (int t = 0; t < nkt; ++t) {
    int b = t & 1;
    // counted wait: force kt's 8 loads; keep kt+1's 8 in flight
    if (t + 1 < nkt)
      asm volatile("s_waitcnt vmcnt(8)" ::: "memory");
    else
      asm volatile("s_waitcnt vmcnt(0)" ::: "memory");
    __builtin_amdgcn_sched_barrier(0);
    __builtin_amdgcn_s_barrier();  // staged data visible to all waves
    __builtin_amdgcn_sched_barrier(0);

    const u16* A = &lds[b][0][0];
    const u16* B = &lds[b][1][0];
    bf16x8 af[4][2], bf[2][2];

    PHASE(0, 0, true, true);
    __builtin_amdgcn_s_barrier();
    PHASE(0, 1, false, true);
    __builtin_amdgcn_s_barrier();
    PHASE(1, 1, true, false);
    __builtin_amdgcn_s_barrier();
    PHASE(1, 0, false, true);

    // all my ds_reads of buf b retired before anyone re-stages into it
    asm volatile("s_waitcnt lgkmcnt(0)" ::: "memory");
    __builtin_amdgcn_sched_barrier(0);
    __builtin_amdgcn_s_barrier();
    __builtin_amdgcn_sched_barrier(0);
    if (t + 2 < nkt) stage(t + 2, b);
  }
#undef PHASE

  // Epilogue: d2 = |x|^2 + |y|^2 - 2 x.y ; out = exp(-gamma*d2)
  // C/D layout: row = fq*4 + r, col = fr (verified m89/m91).
  float gamma = gptr[0];
  float ysv[4];
  #pragma unroll
  for (int n = 0; n < 4; ++n) ysv[n] = ysq[bcol + wn * 64 + n * 16 + fr];
  #pragma unroll
  for (int m = 0; m < 8; ++m) {
    #pragma unroll
    for (int r = 0; r < 4; ++r) {
      int i = brow + wm * 128 + m * 16 + fq * 4 + r;
      float xs = xsq[i];
      size_t ro = (size_t)i * M;
      #pragma unroll
      for (int n = 0; n < 4; ++n) {
        int j = bcol + wn * 64 + n * 16 + fr;
        float d2 = fmaxf(xs + ysv[n] - 2.0f * acc[m][n][r], 0.0f);
        out[ro + j] = __expf(-gamma * d2);
      }
    }
  }
}

// ---------------------------------------------------------------------------
// Fallback: fp32 LDS-tiled, slow but correct for odd shapes.
// ---------------------------------------------------------------------------
__global__ __launch_bounds__(256) void rbf_naive(
    const float* __restrict__ x, const float* __restrict__ y,
    const float* __restrict__ gptr, float* __restrict__ out,
    int N, int M, int D) {
  __shared__ float xs[16][17];
  __shared__ float ys[16][17];
  int nbn = M / 16;
  int brow = (blockIdx.x / nbn) * 16;
  int bcol = (blockIdx.x % nbn) * 16;
  int ti = threadIdx.x >> 4, tj = threadIdx.x & 15;
  float dacc = 0.f, xacc = 0.f, yacc = 0.f;
  for (int k0 = 0; k0 < D; k0 += 16) {
    xs[ti][tj] = x[(size_t)(brow + ti) * D + k0 + tj];
    ys[ti][tj] = y[(size_t)(bcol + ti) * D + k0 + tj];
    __syncthreads();
    #pragma unroll
    for (int kk = 0; kk < 16; ++kk) {
      float xv = xs[ti][kk], yv = ys[tj][kk];
      dacc += xv * yv;
      xacc += xv * xv;
      yacc += yv * yv;
    }
    __syncthreads();
  }
  float gamma = gptr[0];
  float d2 = fmaxf(xacc + yacc - 2.f * dacc, 0.f);
  out[(size_t)(brow + ti) * M + (bcol + tj)] = __expf(-gamma * d2);
}

// ---------------------------------------------------------------------------
extern "C" void kernel_launch(void* const* d_in, const int* in_sizes, int n_in,
                              void* d_out, int out_size, void* d_ws,
                              size_t ws_size, hipStream_t stream) {
  const float* x = (const float*)d_in[0];
  const float* y = (const float*)d_in[1];
  const float* g = (const float*)d_in[2];
  float* out = (float*)d_out;

  const int D = 512;
  const int N = in_sizes[0] / D;
  const int M = in_sizes[1] / D;

  size_t need = (size_t)(N + M) * D * sizeof(u16) + (size_t)(N + M) * sizeof(float);
  bool shapes_ok = (N % BM == 0) && (M % BN == 0) && (D % BK == 0) && (D / BK >= 2);

  if (ws_size >= need && shapes_ok) {
    u16* xb = (u16*)d_ws;
    u16* yb = xb + (size_t)N * D;
    float* xsq = (float*)(yb + (size_t)M * D);
    float* ysq = xsq + N;

    rbf_prep<<<N + M, 128, 0, stream>>>(x, y, xb, yb, xsq, ysq, N, M, D);
    int nwg = (N / BM) * (M / BN);
    rbf_gemm<<<nwg, 512, 0, stream>>>(xb, yb, xsq, ysq, g, out, N, M, D);
  } else {
    rbf_naive<<<(N / 16) * (M / 16), 256, 0, stream>>>(x, y, g, out, N, M, D);
  }
}